// Round 7
// baseline (143.066 us; speedup 1.0000x reference)
//
#include <hip/hip_runtime.h>

typedef unsigned short u16;
typedef unsigned int u32;
typedef unsigned long long u64;
typedef __bf16 bf16x8 __attribute__((ext_vector_type(8)));
typedef float f32x4 __attribute__((ext_vector_type(4)));

__device__ __forceinline__ u16 f2bf(float f) {
  u32 u = __float_as_uint(f);
  return (u16)((u + 0x7fffu + ((u >> 16) & 1u)) >> 16);  // RNE
}
__device__ __forceinline__ float bf2f(u16 h) {
  return __uint_as_float(((u32)h) << 16);
}

// async global->LDS, 16B per lane; LDS dest = wave-uniform base + lane*16,
// global src is PER-LANE (verified in k_gemm R5 + k_attn R6)
__device__ __forceinline__ void glds16(const void* g, void* s) {
  __builtin_amdgcn_global_load_lds(
      (__attribute__((address_space(1))) void*)(u64)g,
      (__attribute__((address_space(3))) void*)(u32)(u64)s, 16, 0, 0);
}

// ---------------- x: fp32 -> bf16 ----------------
__global__ __launch_bounds__(256) void k_convert_x(const float4* __restrict__ x4,
                                                   uint2* __restrict__ o4, int n4) {
  int i = blockIdx.x * 256 + threadIdx.x;
  int stride = gridDim.x * 256;
  for (; i < n4; i += stride) {
    float4 v = x4[i];
    uint2 o;
    o.x = (u32)f2bf(v.x) | ((u32)f2bf(v.y) << 16);
    o.y = (u32)f2bf(v.z) | ((u32)f2bf(v.w) << 16);
    o4[i] = o;
  }
}

// ---------------- weight prep ----------------
__global__ __launch_bounds__(256) void k_prep_w(
    const float* __restrict__ Wq, const float* __restrict__ bq,
    const float* __restrict__ Wkv, const float* __restrict__ bkv,
    const float* __restrict__ Wproj,
    u16* __restrict__ W1t, float* __restrict__ b1, u16* __restrict__ Wpt) {
  int n = blockIdx.x, k = threadIdx.x;
  if (n < 768) {
    float v = (n < 256) ? Wq[k * 256 + n] * 0.125f : Wkv[k * 512 + (n - 256)];
    W1t[n * 256 + k] = f2bf(v);
    if (k == 0) b1[n] = (n < 256) ? bq[n] * 0.125f : bkv[n - 256];
  } else {
    int nn = n - 768;
    Wpt[nn * 256 + k] = f2bf(Wproj[k * 256 + nn]);
  }
}

// ---------------- GEMM: C[M x N] = A[M x 256] * Bt[N x 256]^T + bias ----------------
// 128x128 tile, BK=32, 4 waves (2x2), 16x16x32 bf16 MFMA.
// T3 minimum 2-phase: double-buffered LDS, STAGE(next) issued before compute(cur),
// ONE barrier per K-step (its implicit vmcnt/lgkmcnt drain covers both hazards:
// cur-buf loads landed at the PREVIOUS barrier; next-buf's old readers passed it).
__global__ __launch_bounds__(256) void k_gemm(const u16* __restrict__ A,
                                              const u16* __restrict__ Bt,
                                              const float* __restrict__ bias,
                                              void* __restrict__ Cout,
                                              int N, int out_bf16) {
  __shared__ u16 As[2][128 * 32];
  __shared__ u16 Bs[2][128 * 32];
  int nt = N >> 7;
  int nwg = gridDim.x;
  int bid = blockIdx.x;
  // XCD-chunked swizzle (nwg % 8 == 0): N-tiles of one M-tile share an XCD L2
  int swz = (bid & 7) * (nwg >> 3) + (bid >> 3);
  int mt = swz / nt;
  int ntile = swz - mt * nt;
  int tid = threadIdx.x;
  int lane = tid & 63, wid = tid >> 6;
  int wm = wid >> 1, wn = wid & 1;
  size_t mbase = (size_t)mt << 7;
  int nbase = ntile << 7;
  int lrow = tid >> 2;
  int lch = (tid & 3) << 3;

  const u16* ag = A + (mbase + (size_t)lrow) * 256 + lch;
  const u16* bg = Bt + ((size_t)(nbase + lrow)) * 256 + lch;
  u32 wbase = ((u32)wid) << 9;   // wave-uniform LDS base (u16 units, w*1024 B)

  f32x4 acc[4][4] = {};

  // prologue: stage kb=0 into buffer 0
  glds16(ag, As[0] + wbase);
  glds16(ag + 64 * 256, As[0] + 2048 + wbase);
  glds16(bg, Bs[0] + wbase);
  glds16(bg + 64 * 256, Bs[0] + 2048 + wbase);
  __syncthreads();

  for (int kb = 0; kb < 8; ++kb) {
    int cur = kb & 1;
    // phase A: issue next tile's staging (latency hides under compute below)
    if (kb < 7) {
      int nx = cur ^ 1;
      glds16(ag + (kb + 1) * 32, As[nx] + wbase);
      glds16(ag + 64 * 256 + (kb + 1) * 32, As[nx] + 2048 + wbase);
      glds16(bg + (kb + 1) * 32, Bs[nx] + wbase);
      glds16(bg + 64 * 256 + (kb + 1) * 32, Bs[nx] + 2048 + wbase);
    }
    // phase B: compute from current buffer
    int r = lane & 15, kq = (lane >> 4) << 3;
    bf16x8 af[4], bfv[4];
#pragma unroll
    for (int m = 0; m < 4; ++m)
      af[m] = *(const bf16x8*)(As[cur] + (wm * 64 + m * 16 + r) * 32 + kq);
#pragma unroll
    for (int n = 0; n < 4; ++n)
      bfv[n] = *(const bf16x8*)(Bs[cur] + (wn * 64 + n * 16 + r) * 32 + kq);
#pragma unroll
    for (int m = 0; m < 4; ++m)
#pragma unroll
      for (int n = 0; n < 4; ++n)
        acc[m][n] = __builtin_amdgcn_mfma_f32_16x16x32_bf16(af[m], bfv[n], acc[m][n], 0, 0, 0);
    __syncthreads();   // implicit vmcnt(0)+lgkmcnt(0) drain: next buf ready
  }

  int cg4 = (lane >> 4) << 2;
  int cl = lane & 15;
#pragma unroll
  for (int m = 0; m < 4; ++m)
#pragma unroll
    for (int n = 0; n < 4; ++n) {
      size_t row0 = mbase + wm * 64 + m * 16 + cg4;
      int col = nbase + wn * 64 + n * 16 + cl;
      float bv = bias[col];
#pragma unroll
      for (int rr = 0; rr < 4; ++rr) {
        float v = acc[m][n][rr] + bv;
        if (out_bf16) ((u16*)Cout)[(row0 + rr) * (size_t)N + col] = f2bf(v);
        else ((float*)Cout)[(row0 + rr) * (size_t)N + col] = v;
      }
    }
}

// ---------------- attention + LePE (R6 VERIFIED version, unchanged) ----------------
__global__ __launch_bounds__(512) void k_attn(const u16* __restrict__ QKV,
                                              const float* __restrict__ lepe_w,
                                              const float* __restrict__ lepe_b,
                                              u16* __restrict__ Obuf) {
  __shared__ u16 BUF[4][128 * 64];   // 0:K 1:Vo 2:Vm 3:Vp, row-major [p][c]
  __shared__ float Mf[8][16][16];    // per-wave partial M (f32)
  __shared__ u16 Mt[4][16][32];      // M^T bf16, K-padded to 32
  __shared__ float lwS[9][16];
  __shared__ float lbS[16];

  int bid = blockIdx.x;
  int t = bid & 127, b = (bid >> 7) & 3, d = bid >> 9;
  int tid = threadIdx.x;
  int w = tid >> 6, l = tid & 63;
  int hh = w & 3, ph = w >> 2;

  ((u32*)Mt)[tid] = 0;
  ((u32*)Mt)[tid + 512] = 0;
  if (tid < 144) lwS[tid >> 4][tid & 15] = lepe_w[(tid & 15) * 9 + (tid >> 4)];
  if (tid < 16) lbS[tid] = lepe_b[tid];

  auto pixof = [&](int line, int p) -> u32 {
    int h, ww;
    if (d == 2)      { h = line; ww = p; }
    else if (d == 0) { h = p; ww = (line - (p + 1)) & 127; }
    else if (d == 1) { h = p; ww = (line + (p + 1)) & 127; }
    else             { h = p; ww = line; }
    return ((u32)(b * 128 + h) << 7) + (u32)ww;
  };

  // ---- Q prefetch into regs ----
  uint4 qreg[4];
  u32 qch = (u32)d * 64 + (u32)hh * 16 + (u32)((l >> 4) & 1) * 8;
#pragma unroll
  for (int k = 0; k < 4; ++k) {
    int p = (ph * 4 + k) * 16 + (l & 15);
    qreg[k] = *(const uint4*)(QKV + (u64)pixof(t, p) * 768 + qch);
  }

  // ---- stage via global_load_lds: wave w -> buffer w&3, p-half w>>2 ----
  {
    int bf = w & 3;
    int line = t;
    u32 choff = (bf == 0) ? (256u + d * 64) : (512u + d * 64);
    bool ok = true;
    if (bf == 2) { line = t - 16; ok = (t >> 4) > 0; }
    if (bf == 3) { line = t + 16; ok = (t >> 4) < 7; }
    u16* Bb = &BUF[bf][0];
    int phh = (w >> 2) * 64;
#pragma unroll
    for (int it = 0; it < 8; ++it) {
      int p0 = phh + it * 8;   // wave-uniform
      if (ok) {
        const u16* g = QKV + (u64)pixof(line, p0 + (l >> 3)) * 768 + choff + (l & 7) * 8;
        glds16(g, Bb + p0 * 64);
      } else {
        *(uint4*)(Bb + p0 * 64 + l * 8) = make_uint4(0, 0, 0, 0);
      }
    }
  }
  __syncthreads();

  // ---- phase 1: wave w = (head hh, p-half ph): partial M = K^T V ----
  {
    u32 cA = (u32)hh * 16 + (u32)(l & 15);
    f32x4 m = {0.f, 0.f, 0.f, 0.f};
#pragma unroll
    for (int kc = 0; kc < 2; ++kc) {
      u32 pc = (u32)ph * 64 + (u32)kc * 32 + (u32)(l >> 4) * 8;
      union { u16 e[8]; bf16x8 v; } ka, vb;
#pragma unroll
      for (int e = 0; e < 8; ++e) {
        ka.e[e] = BUF[0][(pc + e) * 64 + cA];
        vb.e[e] = BUF[1][(pc + e) * 64 + cA];
      }
      m = __builtin_amdgcn_mfma_f32_16x16x32_bf16(ka.v, vb.v, m, 0, 0, 0);
    }
    *(f32x4*)&Mf[w][l & 15][(l >> 4) * 4] = m;
  }
  __syncthreads();

  // ---- combine halves -> Mt bf16 ----
  if (tid < 256) {
    int ch = tid >> 6;
    int c2 = (tid >> 2) & 15;
    int c1g = (tid & 3) * 4;
    f32x4 a = *(const f32x4*)&Mf[ch][c2][c1g];
    f32x4 bb = *(const f32x4*)&Mf[ch + 4][c2][c1g];
    u16* dst = &Mt[ch][c2][c1g];
    dst[0] = f2bf(a[0] + bb[0]);
    dst[1] = f2bf(a[1] + bb[1]);
    dst[2] = f2bf(a[2] + bb[2]);
    dst[3] = f2bf(a[3] + bb[3]);
  }
  __syncthreads();

  // ---- phase 2: O = Q*M + LePE conv + permuted store ----
  union UB { uint4 u; bf16x8 v; } mb;
  mb.u = *(const uint4*)((const char*)Mt + (u32)hh * 1024 + (u32)(l & 15) * 64 +
                         (u32)(l >> 4) * 16);

  float wreg[9];
#pragma unroll
  for (int k = 0; k < 9; ++k) wreg[k] = lwS[k][l & 15];
  float lbias = lbS[l & 15];
  int nf = (t >> 2) & 3;
  int tp = (t & 112) | ((t & 3) << 2) | hh;
  u32 och = (u32)d * 64 + (u32)nf * 16 + (u32)(l & 15);
  u32 cc = (u32)hh * 16 + (u32)(l & 15);
  int g = l >> 4;

#pragma unroll
  for (int k = 0; k < 4; ++k) {
    int pt = ph * 4 + k;
    union UA { uint4 u; bf16x8 v; } qa;
    qa.u = qreg[k];
    f32x4 o = {0.f, 0.f, 0.f, 0.f};
    o = __builtin_amdgcn_mfma_f32_16x16x32_bf16(qa.v, mb.v, o, 0, 0, 0);

    int p0 = pt * 16 + g * 4;
    float tap[3][6];
    const u32 bufid[3] = {2u, 1u, 3u};
#pragma unroll
    for (int r = 0; r < 3; ++r) {
      const u16* Bp = &BUF[bufid[r]][0];
#pragma unroll
      for (int j = 0; j < 6; ++j) {
        int pr = p0 - 1 + j;
        bool okr = (pr >= 0) && (pr < 128);
        tap[r][j] = okr ? bf2f(Bp[(u32)pr * 64 + cc]) : 0.f;
      }
    }
#pragma unroll
    for (int rr = 0; rr < 4; ++rr) {
      float acc = o[rr] + lbias;
#pragma unroll
      for (int r = 0; r < 3; ++r)
#pragma unroll
        for (int bb = 0; bb < 3; ++bb)
          acc += wreg[r * 3 + bb] * tap[r][rr + bb];
      int p = p0 + rr;
      int ho, wo;
      if (d == 2)      { ho = tp; wo = p; }
      else if (d == 0) { ho = p; wo = (tp - (p + 1)) & 127; }
      else if (d == 1) { ho = p; wo = (tp + (p + 1)) & 127; }
      else             { ho = p; wo = tp; }
      u32 opix = ((u32)(b * 128 + ho) << 7) + (u32)wo;
      Obuf[opix * 256 + och] = f2bf(acc);
    }
  }
}

// ---------------- launch ----------------
extern "C" void kernel_launch(void* const* d_in, const int* in_sizes, int n_in,
                              void* d_out, int out_size, void* d_ws, size_t ws_size,
                              hipStream_t stream) {
  (void)in_sizes; (void)n_in; (void)out_size; (void)ws_size;
  const float* x     = (const float*)d_in[0];
  const float* Wq    = (const float*)d_in[1];
  const float* bq    = (const float*)d_in[2];
  const float* Wkv   = (const float*)d_in[3];
  const float* bkv   = (const float*)d_in[4];
  const float* Wproj = (const float*)d_in[5];
  const float* bproj = (const float*)d_in[6];
  const float* lepe_w = (const float*)d_in[7];
  const float* lepe_b = (const float*)d_in[8];
  float* out = (float*)d_out;

  char* ws = (char*)d_ws;
  u16* Xbf   = (u16*)(ws + 0);           //  65536x256 bf16 = 32 MB
  u16* QKV   = (u16*)(ws + 33554432);    //  65536x768 bf16 = 96 MB
  u16* Obuf  = (u16*)(ws + 134217728);   //  65536x256 bf16 = 32 MB
  u16* W1t   = (u16*)(ws + 167772160);   //  768x256 bf16
  u16* Wpt   = (u16*)(ws + 168165376);   //  256x256 bf16
  float* b1  = (float*)(ws + 168296448); //  768 f32

  k_convert_x<<<2048, 256, 0, stream>>>((const float4*)x, (uint2*)Xbf, 16777216 / 4);
  k_prep_w<<<1024, 256, 0, stream>>>(Wq, bq, Wkv, bkv, Wproj, W1t, b1, Wpt);
  k_gemm<<<512 * 6, 256, 0, stream>>>(Xbf, W1t, b1, QKV, 768, 1);
  k_attn<<<2048, 512, 0, stream>>>(QKV, lepe_w, lepe_b, Obuf);
  k_gemm<<<512 * 2, 256, 0, stream>>>(Obuf, Wpt, bproj, out, 256, 0);
}